// Round 18
// baseline (159.657 us; speedup 1.0000x reference)
//
#include <hip/hip_runtime.h>
#include <hip/hip_bf16.h>

#define N_NODES 100000
#define D_IN 128
#define HID 256
#define D_OUT 64
#define TR 32
#define NBUK 196   // dst>>9 buckets of 512 nodes
#define BSH 9
#define MGRID 3125 // one 32-row tile per block

typedef __attribute__((ext_vector_type(8))) short bf8;
typedef __attribute__((ext_vector_type(4))) float f4;

static __device__ __forceinline__ unsigned short f2bf(float f) {
    __hip_bfloat16 h = __float2bfloat16(f);
    return *reinterpret_cast<unsigned short*>(&h);
}
static __device__ __forceinline__ float bflo(unsigned int u) { return __uint_as_float(u << 16); }
static __device__ __forceinline__ float bfhi(unsigned int u) { return __uint_as_float(u & 0xffff0000u); }

static __device__ __forceinline__ void fma8(float* a, float w, uint4 u) {
    a[0] += w * bflo(u.x); a[1] += w * bfhi(u.x);
    a[2] += w * bflo(u.y); a[3] += w * bfhi(u.y);
    a[4] += w * bflo(u.z); a[5] += w * bfhi(u.z);
    a[6] += w * bflo(u.w); a[7] += w * bfhi(u.w);
}
static __device__ __forceinline__ void fma4(float* a, float w, uint2 u) {
    a[0] += w * bflo(u.x); a[1] += w * bfhi(u.x);
    a[2] += w * bflo(u.y); a[3] += w * bfhi(u.y);
}

// ---------------- fused prep: cvt_x | cvt_w1 | cvt_w2 | per-block bucket histograms ----------------

__global__ __launch_bounds__(256) void k_prep(const float* __restrict__ x,
                                              unsigned long long* __restrict__ xb,
                                              const float* __restrict__ W1,
                                              unsigned short* __restrict__ W1t,
                                              const float* __restrict__ W2,
                                              unsigned short* __restrict__ W2t,
                                              const int* __restrict__ dst, int E,
                                              int* __restrict__ hist2d) {
    int b = blockIdx.x, t = threadIdx.x;
    if (b < 12500) {
        int i = b * 256 + t;  // float4 index over x
        float4 v = ((const float4*)x)[i];
        unsigned long long o = (unsigned long long)f2bf(v.x) |
                               ((unsigned long long)f2bf(v.y) << 16) |
                               ((unsigned long long)f2bf(v.z) << 32) |
                               ((unsigned long long)f2bf(v.w) << 48);
        xb[i] = o;
    } else if (b < 12628) {
        int i = (b - 12500) * 256 + t;
        int n = i >> 7, k = i & 127;
        W1t[i] = f2bf(W1[k * HID + n]);
    } else if (b < 12692) {
        int i = (b - 12628) * 256 + t;
        int n = i >> 8, k = i & 255;
        W2t[i] = f2bf(W2[k * D_OUT + n]);
    } else {
        int hb = b - 12692;
        __shared__ int h[NBUK];
        if (t < NBUK) h[t] = 0;
        __syncthreads();
        int base = hb * 4096;
        for (int j = 0; j < 16; j++) {
            int e = base + j * 256 + t;
            if (e < E) atomicAdd(&h[dst[e] >> BSH], 1);
        }
        __syncthreads();
        if (t < NBUK) hist2d[hb * NBUK + t] = h[t];
    }
}

// ---------------- scanB1: per-bucket scan over edge-blocks (grid = NBUK) ----------------

__global__ __launch_bounds__(256) void k_scanB1(const int* __restrict__ hist2d,
                                                int* __restrict__ blockbase,
                                                int* __restrict__ bsumB, int nbb) {
    __shared__ int s[256];
    int u = blockIdx.x, t = threadIdx.x;
    int v = (t < nbb) ? hist2d[t * NBUK + u] : 0;
    s[t] = v;
    __syncthreads();
    for (int off = 1; off < 256; off <<= 1) {
        int w = (t >= off) ? s[t - off] : 0;
        __syncthreads();
        s[t] += w;
        __syncthreads();
    }
    if (t < nbb) blockbase[t * NBUK + u] = s[t] - v;  // exclusive, bucket-local
    if (t == 255) bsumB[u] = s[255];                  // bucket total
}

// local exclusive scan of bucket totals into exs[0..NBUK]
static __device__ __forceinline__ void bucket_scan(const int* __restrict__ bsumB,
                                                   int* s, int* exs, int t) {
    int v = (t < NBUK) ? bsumB[t] : 0;
    s[t] = v;
    __syncthreads();
    for (int off = 1; off < 256; off <<= 1) {
        int w = (t >= off) ? s[t - off] : 0;
        __syncthreads();
        s[t] += w;
        __syncthreads();
    }
    if (t < NBUK) exs[t] = s[t] - v;
    if (t == NBUK - 1) exs[NBUK] = s[t];
    __syncthreads();
}

// ---------------- bin: deterministic bases, LDS rank only. record = (dst&511)<<17 | src ----------------

__global__ __launch_bounds__(256) void k_bin(const int* __restrict__ src,
                                             const int* __restrict__ dst, int E,
                                             const int* __restrict__ blockbase,
                                             const int* __restrict__ bsumB,
                                             unsigned int* __restrict__ bin) {
    __shared__ int s[256], exs[NBUK + 1];
    __shared__ int baseL[NBUK], rankL[NBUK];
    int t = threadIdx.x;
    bucket_scan(bsumB, s, exs, t);
    if (t < NBUK) {
        baseL[t] = exs[t] + blockbase[blockIdx.x * NBUK + t];
        rankL[t] = 0;
    }
    __syncthreads();
    int base = blockIdx.x * 4096;
    for (int j = 0; j < 16; j++) {
        int e = base + j * 256 + t;
        if (e < E) {
            int sv = src[e], d = dst[e];
            int bu = d >> BSH;
            int r = atomicAdd(&rankL[bu], 1);
            bin[baseL[bu] + r] = ((unsigned int)(d & 511) << 17) | (unsigned int)sv;
        }
    }
}

// ---------------- cntscan: per-bucket counts + scan -> FINAL row_ptr + dinv ----------------

__global__ __launch_bounds__(256) void k_cntscan(const unsigned int* __restrict__ bin,
                                                 const int* __restrict__ bsumB,
                                                 int* __restrict__ row_ptr,
                                                 float* __restrict__ dinv) {
    __shared__ int sb[256], exs[NBUK + 1];
    __shared__ int c[512];
    __shared__ int s[256];
    int b = blockIdx.x, t = threadIdx.x;
    bucket_scan(bsumB, sb, exs, t);
    int lo = exs[b], hi = exs[b + 1];
    c[t] = 0;
    c[t + 256] = 0;
    __syncthreads();
    for (int e = lo + t; e < hi; e += 256) atomicAdd(&c[bin[e] >> 17], 1);
    __syncthreads();
    int a0 = c[2 * t], a1 = c[2 * t + 1];
    s[t] = a0 + a1;
    __syncthreads();
    for (int off = 1; off < 256; off <<= 1) {
        int u = (t >= off) ? s[t - off] : 0;
        __syncthreads();
        s[t] += u;
        __syncthreads();
    }
    int ex = (t > 0) ? s[t - 1] : 0;
    int n0 = (b << BSH) + 2 * t;
    if (n0 < N_NODES) {
        row_ptr[n0] = lo + ex;  // FINAL global edge offset
        dinv[n0] = rsqrtf((float)a0 + 1.0f);
    }
    if (n0 + 1 < N_NODES) {
        row_ptr[n0 + 1] = lo + ex + a0;
        dinv[n0 + 1] = rsqrtf((float)a1 + 1.0f);
    }
    if (b == NBUK - 1 && t == 255) row_ptr[N_NODES] = exs[NBUK];  // sentinel = E
}

// ---------------- place: cursors from final row_ptr; write cw ----------------

__global__ __launch_bounds__(256) void k_place(const unsigned int* __restrict__ bin,
                                               const int* __restrict__ bsumB,
                                               const int* __restrict__ row_ptr,
                                               const float* __restrict__ dinv,
                                               int2* __restrict__ cw) {
    __shared__ int sb[256], exs[NBUK + 1];
    __shared__ int cur[512];
    __shared__ float dl[512];
    int b = blockIdx.x, t = threadIdx.x;
    bucket_scan(bsumB, sb, exs, t);
    int node0 = b << BSH;
    int nbn = N_NODES - node0;
    if (nbn > 512) nbn = 512;
    if (t < nbn) {
        cur[t] = row_ptr[node0 + t];
        dl[t] = dinv[node0 + t];
    }
    if (t + 256 < nbn) {
        cur[t + 256] = row_ptr[node0 + t + 256];
        dl[t + 256] = dinv[node0 + t + 256];
    }
    __syncthreads();
    int lo = exs[b], hi = exs[b + 1];
    for (int e = lo + t; e < hi; e += 256) {
        unsigned int rec = bin[e];
        int sv = rec & 0x1FFFF;
        int dloc = rec >> 17;
        int pos = atomicAdd(&cur[dloc], 1);
        int2 v;
        v.x = sv;
        v.y = __float_as_int(dinv[sv] * dl[dloc]);
        cw[pos] = v;
    }
}

// ---------------- layer-1 pull: 4 nodes/wave, 16 lanes/node, shfl-broadcast cw ----------------

__global__ __launch_bounds__(256) void k_pull1(const int* __restrict__ row_ptr,
                                               const int2* __restrict__ cw,
                                               const uint4* __restrict__ xb4,
                                               const float* __restrict__ dinv,
                                               uint4* __restrict__ agg4) {
    int wave = (blockIdx.x * 256 + threadIdx.x) >> 6;
    int lane = threadIdx.x & 63;
    int g = lane >> 4, l = lane & 15;
    int gbase = g << 4;
    int node = wave * 4 + g;  // grid sized exactly
    int beg = row_ptr[node], end = row_ptr[node + 1];
    float di = dinv[node];
    float a[8] = {0, 0, 0, 0, 0, 0, 0, 0};
    fma8(a, di * di, xb4[(size_t)node * 16 + l]);

    for (int base = beg; base < end; base += 16) {
        int idx = base + l;
        int2 cl = cw[(idx < end) ? idx : beg];
        float wl = (idx < end) ? __int_as_float(cl.y) : 0.f;
        int sl = cl.x;
        int cnt = end - base;
        if (cnt > 16) cnt = 16;
        int s0 = __shfl(sl, gbase + 0), s1 = __shfl(sl, gbase + 1);
        int s2 = __shfl(sl, gbase + 2), s3 = __shfl(sl, gbase + 3);
        float w0 = __shfl(wl, gbase + 0), w1 = __shfl(wl, gbase + 1);
        float w2 = __shfl(wl, gbase + 2), w3 = __shfl(wl, gbase + 3);
        uint4 u0 = xb4[(size_t)s0 * 16 + l];
        uint4 u1 = xb4[(size_t)s1 * 16 + l];
        uint4 u2 = xb4[(size_t)s2 * 16 + l];
        uint4 u3 = xb4[(size_t)s3 * 16 + l];
        for (int j = 4; j < cnt; j += 4) {
            int t0 = __shfl(sl, gbase + j + 0), t1 = __shfl(sl, gbase + j + 1);
            int t2 = __shfl(sl, gbase + j + 2), t3 = __shfl(sl, gbase + j + 3);
            float x0 = __shfl(wl, gbase + j + 0), x1 = __shfl(wl, gbase + j + 1);
            float x2 = __shfl(wl, gbase + j + 2), x3 = __shfl(wl, gbase + j + 3);
            uint4 v0 = xb4[(size_t)t0 * 16 + l];
            uint4 v1 = xb4[(size_t)t1 * 16 + l];
            uint4 v2 = xb4[(size_t)t2 * 16 + l];
            uint4 v3 = xb4[(size_t)t3 * 16 + l];
            fma8(a, w0, u0);
            fma8(a, w1, u1);
            fma8(a, w2, u2);
            fma8(a, w3, u3);
            s0 = t0; s1 = t1; s2 = t2; s3 = t3;
            w0 = x0; w1 = x1; w2 = x2; w3 = x3;
            u0 = v0; u1 = v1; u2 = v2; u3 = v3;
        }
        fma8(a, w0, u0);
        fma8(a, w1, u1);
        fma8(a, w2, u2);
        fma8(a, w3, u3);
    }
    uint4 o;
    o.x = (unsigned int)f2bf(a[0]) | ((unsigned int)f2bf(a[1]) << 16);
    o.y = (unsigned int)f2bf(a[2]) | ((unsigned int)f2bf(a[3]) << 16);
    o.z = (unsigned int)f2bf(a[4]) | ((unsigned int)f2bf(a[5]) << 16);
    o.w = (unsigned int)f2bf(a[6]) | ((unsigned int)f2bf(a[7]) << 16);
    agg4[(size_t)node * 16 + l] = o;
}

// ---------------- fused GEMM chain (MFMA): one 32-row tile per block ----------------
// weights hoisted to regs once per block; A direct from global (L2-hot);
// m written COMPACT (N x 64 bf16). Grid 3125 -> ~12 blocks/CU queued, 4 resident.

__global__ __launch_bounds__(256) void k_fused_mfma(const unsigned short* __restrict__ agg,
                                                    const unsigned short* __restrict__ W1t,
                                                    const float* __restrict__ b1,
                                                    const unsigned short* __restrict__ W2t,
                                                    unsigned short* __restrict__ mb) {
    __shared__ char sH[TR * HID * 2];   // 16 KB, row stride 512B
    int t = threadIdx.x, wave = t >> 6, lane = t & 63;
    int lr = lane & 15, lg = lane >> 4;

    bf8 w1f[4][4];
#pragma unroll
    for (int kk = 0; kk < 4; kk++)
#pragma unroll
        for (int tt = 0; tt < 4; tt++)
            w1f[kk][tt] = *(const bf8*)(W1t + (size_t)(wave * 64 + tt * 16 + lr) * D_IN + kk * 32 + lg * 8);
    bf8 w2f[8];
#pragma unroll
    for (int kk = 0; kk < 8; kk++)
        w2f[kk] = *(const bf8*)(W2t + (size_t)(wave * 16 + lr) * HID + kk * 32 + lg * 8);
    float bias[4];
#pragma unroll
    for (int tt = 0; tt < 4; tt++) bias[tt] = b1[wave * 64 + tt * 16 + lr];

    size_t row0 = (size_t)blockIdx.x * TR;

    f4 acc1[4][2];
#pragma unroll
    for (int tt = 0; tt < 4; tt++)
#pragma unroll
        for (int h = 0; h < 2; h++) acc1[tt][h] = (f4){0.f, 0.f, 0.f, 0.f};

#pragma unroll
    for (int kk = 0; kk < 4; kk++) {
        bf8 a0 = *(const bf8*)(agg + (row0 + lr) * 128 + kk * 32 + lg * 8);
        bf8 a1 = *(const bf8*)(agg + (row0 + 16 + lr) * 128 + kk * 32 + lg * 8);
#pragma unroll
        for (int tt = 0; tt < 4; tt++) {
            acc1[tt][0] = __builtin_amdgcn_mfma_f32_16x16x32_bf16(a0, w1f[kk][tt], acc1[tt][0], 0, 0, 0);
            acc1[tt][1] = __builtin_amdgcn_mfma_f32_16x16x32_bf16(a1, w1f[kk][tt], acc1[tt][1], 0, 0, 0);
        }
    }

#pragma unroll
    for (int tt = 0; tt < 4; tt++) {
        int colc = wave * 64 + tt * 16 + lr;
#pragma unroll
        for (int h = 0; h < 2; h++) {
#pragma unroll
            for (int ri = 0; ri < 4; ri++) {
                int row = h * 16 + lg * 4 + ri;
                float hv = acc1[tt][h][ri] + bias[tt];
                hv = hv > 0.f ? hv : 0.f;
                *(unsigned short*)(sH + ((row * 512 + colc * 2) ^ ((row & 7) << 4))) = f2bf(hv);
            }
        }
    }
    __syncthreads();

    f4 acc2[2];
    acc2[0] = (f4){0.f, 0.f, 0.f, 0.f};
    acc2[1] = (f4){0.f, 0.f, 0.f, 0.f};
#pragma unroll
    for (int kk = 0; kk < 8; kk++) {
        bf8 a0 = *(const bf8*)(sH + ((lr * 512 + kk * 64 + lg * 16) ^ ((lr & 7) << 4)));
        bf8 a1 = *(const bf8*)(sH + (((16 + lr) * 512 + kk * 64 + lg * 16) ^ (((16 + lr) & 7) << 4)));
        acc2[0] = __builtin_amdgcn_mfma_f32_16x16x32_bf16(a0, w2f[kk], acc2[0], 0, 0, 0);
        acc2[1] = __builtin_amdgcn_mfma_f32_16x16x32_bf16(a1, w2f[kk], acc2[1], 0, 0, 0);
    }
    int colc = wave * 16 + lr;
#pragma unroll
    for (int h = 0; h < 2; h++)
#pragma unroll
        for (int ri = 0; ri < 4; ri++) {
            int row = h * 16 + lg * 4 + ri;
            mb[(row0 + row) * D_OUT + colc] = f2bf(acc2[h][ri]);
        }
}

// ---------------- layer-2 pull: 4 nodes/wave, 16 lanes/node, shfl-broadcast cw ----------------
// m rows: COMPACT 64 bf16 = 16 uint2 per row (12.8 MB working set)

__global__ __launch_bounds__(256) void k_pull2(const int* __restrict__ row_ptr,
                                               const int2* __restrict__ cw,
                                               const uint2* __restrict__ m2,
                                               const float* __restrict__ dinv,
                                               const float* __restrict__ b2,
                                               float4* __restrict__ out4) {
    int wave = (blockIdx.x * 256 + threadIdx.x) >> 6;
    int lane = threadIdx.x & 63;
    int g = lane >> 4, l = lane & 15;
    int gbase = g << 4;
    int node = wave * 4 + g;
    int beg = row_ptr[node], end = row_ptr[node + 1];
    float di = dinv[node];
    float a[4] = {0, 0, 0, 0};
    fma4(a, di * di, m2[(size_t)node * 16 + l]);

    for (int base = beg; base < end; base += 16) {
        int idx = base + l;
        int2 cl = cw[(idx < end) ? idx : beg];
        float wl = (idx < end) ? __int_as_float(cl.y) : 0.f;
        int sl = cl.x;
        int cnt = end - base;
        if (cnt > 16) cnt = 16;
        int s0 = __shfl(sl, gbase + 0), s1 = __shfl(sl, gbase + 1);
        int s2 = __shfl(sl, gbase + 2), s3 = __shfl(sl, gbase + 3);
        float w0 = __shfl(wl, gbase + 0), w1 = __shfl(wl, gbase + 1);
        float w2 = __shfl(wl, gbase + 2), w3 = __shfl(wl, gbase + 3);
        uint2 u0 = m2[(size_t)s0 * 16 + l];
        uint2 u1 = m2[(size_t)s1 * 16 + l];
        uint2 u2 = m2[(size_t)s2 * 16 + l];
        uint2 u3 = m2[(size_t)s3 * 16 + l];
        for (int j = 4; j < cnt; j += 4) {
            int t0 = __shfl(sl, gbase + j + 0), t1 = __shfl(sl, gbase + j + 1);
            int t2 = __shfl(sl, gbase + j + 2), t3 = __shfl(sl, gbase + j + 3);
            float x0 = __shfl(wl, gbase + j + 0), x1 = __shfl(wl, gbase + j + 1);
            float x2 = __shfl(wl, gbase + j + 2), x3 = __shfl(wl, gbase + j + 3);
            uint2 v0 = m2[(size_t)t0 * 16 + l];
            uint2 v1 = m2[(size_t)t1 * 16 + l];
            uint2 v2 = m2[(size_t)t2 * 16 + l];
            uint2 v3 = m2[(size_t)t3 * 16 + l];
            fma4(a, w0, u0);
            fma4(a, w1, u1);
            fma4(a, w2, u2);
            fma4(a, w3, u3);
            s0 = t0; s1 = t1; s2 = t2; s3 = t3;
            w0 = x0; w1 = x1; w2 = x2; w3 = x3;
            u0 = v0; u1 = v1; u2 = v2; u3 = v3;
        }
        fma4(a, w0, u0);
        fma4(a, w1, u1);
        fma4(a, w2, u2);
        fma4(a, w3, u3);
    }
    float4 bv = ((const float4*)b2)[l];
    float4 o;
    o.x = a[0] + bv.x;
    o.y = a[1] + bv.y;
    o.z = a[2] + bv.z;
    o.w = a[3] + bv.w;
    out4[(size_t)node * 16 + l] = o;
}

// ---------------- launch ----------------

extern "C" void kernel_launch(void* const* d_in, const int* in_sizes, int n_in,
                              void* d_out, int out_size, void* d_ws, size_t ws_size,
                              hipStream_t stream) {
    const float* x  = (const float*)d_in[0];
    const int*   ei = (const int*)d_in[1];
    const float* W1 = (const float*)d_in[2];
    const float* b1 = (const float*)d_in[3];
    const float* W2 = (const float*)d_in[4];
    const float* b2 = (const float*)d_in[5];
    float* out = (float*)d_out;

    const int E = in_sizes[1] / 2;
    const int* src = ei;
    const int* dst = ei + E;

    // workspace layout — ends at 71,299,328 B (d_ws = 256 MiB per harness poison fills)
    char* ws = (char*)d_ws;
    int* row_ptr        = (int*)(ws + 0);              // 100001 ints
    int2* cw            = (int2*)(ws + 400640);        // 800000 int2 (6.4 MB)
    float* dinv         = (float*)(ws + 6800640);      // 100000 f
    unsigned short* W1t = (unsigned short*)(ws + 7201024);   // 256*128 bf16
    unsigned short* W2t = (unsigned short*)(ws + 7266560);   // 64*256 bf16
    unsigned short* xb  = (unsigned short*)(ws + 7299328);   // N*128 bf16 (25.6 MB)
    unsigned short* aggb = (unsigned short*)(ws + 32899328); // N*128 bf16 (25.6 MB)
    unsigned short* mb  = (unsigned short*)(ws + 58499328);  // N*64 bf16 (12.8 MB) compact m
    // scratch aliased into aggb region (all dead before k_pull1 writes aggb)
    unsigned int* bin   = (unsigned int*)aggb;                    // E uints (3.2 MB)
    int* hist2d         = (int*)((char*)aggb + 3200256);          // NBB*NBUK ints
    int* blockbase      = (int*)((char*)aggb + 3354112);          // NBB*NBUK ints
    int* bsumB          = (int*)((char*)aggb + 3507968);          // NBUK ints

    const int NBB = (E + 4095) / 4096;  // 196 edge blocks

    // 1. prep: cvt_x | cvt_w1 | cvt_w2 | hist2d rows
    k_prep<<<12692 + NBB, 256, 0, stream>>>(x, (unsigned long long*)xb, W1, W1t, W2, W2t,
                                            dst, E, hist2d);
    // 2. per-bucket scan over edge-blocks
    k_scanB1<<<NBUK, 256, 0, stream>>>(hist2d, blockbase, bsumB, NBB);
    // 3. bin edges by dst bucket
    k_bin<<<NBB, 256, 0, stream>>>(src, dst, E, blockbase, bsumB, bin);
    // 4. per-bucket counts + scan -> FINAL row_ptr + dinv
    k_cntscan<<<NBUK, 256, 0, stream>>>(bin, bsumB, row_ptr, dinv);
    // 5. place cw records
    k_place<<<NBUK, 256, 0, stream>>>(bin, bsumB, row_ptr, dinv, cw);
    // 6. layer-1 pull (shfl-broadcast cw, SW-pipelined gathers)
    k_pull1<<<6250, 256, 0, stream>>>(row_ptr, cw, (const uint4*)xb, dinv, (uint4*)aggb);
    // 7. fused MFMA GEMM chain -> compact m (1 tile/block, high occupancy)
    k_fused_mfma<<<MGRID, 256, 0, stream>>>(aggb, W1t, b1, W2t, mb);
    // 8. layer-2 pull (compact m gathers)
    k_pull2<<<6250, 256, 0, stream>>>(row_ptr, cw, (const uint2*)mb, dinv, b2, (float4*)out);
}

// Round 19
// 145.394 us; speedup vs baseline: 1.0981x; 1.0981x over previous
//
#include <hip/hip_runtime.h>
#include <hip/hip_bf16.h>

#define N_NODES 100000
#define D_IN 128
#define HID 256
#define D_OUT 64
#define TR 32
#define NBUK 196   // dst>>9 buckets of 512 nodes
#define BSH 9
#define MGRID 1042 // 3 tiles per block: 1042*3 = 3126 >= 3125 (guarded)
#define TPB 3

typedef __attribute__((ext_vector_type(8))) short bf8;
typedef __attribute__((ext_vector_type(4))) float f4;

static __device__ __forceinline__ unsigned short f2bf(float f) {
    __hip_bfloat16 h = __float2bfloat16(f);
    return *reinterpret_cast<unsigned short*>(&h);
}
static __device__ __forceinline__ float bflo(unsigned int u) { return __uint_as_float(u << 16); }
static __device__ __forceinline__ float bfhi(unsigned int u) { return __uint_as_float(u & 0xffff0000u); }

static __device__ __forceinline__ void fma8(float* a, float w, uint4 u) {
    a[0] += w * bflo(u.x); a[1] += w * bfhi(u.x);
    a[2] += w * bflo(u.y); a[3] += w * bfhi(u.y);
    a[4] += w * bflo(u.z); a[5] += w * bfhi(u.z);
    a[6] += w * bflo(u.w); a[7] += w * bfhi(u.w);
}
static __device__ __forceinline__ void fma4(float* a, float w, uint2 u) {
    a[0] += w * bflo(u.x); a[1] += w * bfhi(u.x);
    a[2] += w * bflo(u.y); a[3] += w * bfhi(u.y);
}

// ---------------- fused prep: cvt_x | cvt_w1 | cvt_w2 | per-block bucket histograms ----------------

__global__ __launch_bounds__(256) void k_prep(const float* __restrict__ x,
                                              unsigned long long* __restrict__ xb,
                                              const float* __restrict__ W1,
                                              unsigned short* __restrict__ W1t,
                                              const float* __restrict__ W2,
                                              unsigned short* __restrict__ W2t,
                                              const int* __restrict__ dst, int E,
                                              int* __restrict__ hist2d) {
    int b = blockIdx.x, t = threadIdx.x;
    if (b < 12500) {
        int i = b * 256 + t;  // float4 index over x
        float4 v = ((const float4*)x)[i];
        unsigned long long o = (unsigned long long)f2bf(v.x) |
                               ((unsigned long long)f2bf(v.y) << 16) |
                               ((unsigned long long)f2bf(v.z) << 32) |
                               ((unsigned long long)f2bf(v.w) << 48);
        xb[i] = o;
    } else if (b < 12628) {
        int i = (b - 12500) * 256 + t;
        int n = i >> 7, k = i & 127;
        W1t[i] = f2bf(W1[k * HID + n]);
    } else if (b < 12692) {
        int i = (b - 12628) * 256 + t;
        int n = i >> 8, k = i & 255;
        W2t[i] = f2bf(W2[k * D_OUT + n]);
    } else {
        int hb = b - 12692;
        __shared__ int h[NBUK];
        if (t < NBUK) h[t] = 0;
        __syncthreads();
        int base = hb * 4096;
        for (int j = 0; j < 16; j++) {
            int e = base + j * 256 + t;
            if (e < E) atomicAdd(&h[dst[e] >> BSH], 1);
        }
        __syncthreads();
        if (t < NBUK) hist2d[hb * NBUK + t] = h[t];
    }
}

// ---------------- scanB1: per-bucket scan over edge-blocks (grid = NBUK) ----------------

__global__ __launch_bounds__(256) void k_scanB1(const int* __restrict__ hist2d,
                                                int* __restrict__ blockbase,
                                                int* __restrict__ bsumB, int nbb) {
    __shared__ int s[256];
    int u = blockIdx.x, t = threadIdx.x;
    int v = (t < nbb) ? hist2d[t * NBUK + u] : 0;
    s[t] = v;
    __syncthreads();
    for (int off = 1; off < 256; off <<= 1) {
        int w = (t >= off) ? s[t - off] : 0;
        __syncthreads();
        s[t] += w;
        __syncthreads();
    }
    if (t < nbb) blockbase[t * NBUK + u] = s[t] - v;  // exclusive, bucket-local
    if (t == 255) bsumB[u] = s[255];                  // bucket total
}

// local exclusive scan of bucket totals into exs[0..NBUK]
static __device__ __forceinline__ void bucket_scan(const int* __restrict__ bsumB,
                                                   int* s, int* exs, int t) {
    int v = (t < NBUK) ? bsumB[t] : 0;
    s[t] = v;
    __syncthreads();
    for (int off = 1; off < 256; off <<= 1) {
        int w = (t >= off) ? s[t - off] : 0;
        __syncthreads();
        s[t] += w;
        __syncthreads();
    }
    if (t < NBUK) exs[t] = s[t] - v;
    if (t == NBUK - 1) exs[NBUK] = s[t];
    __syncthreads();
}

// ---------------- bin: deterministic bases, LDS rank only. record = (dst&511)<<17 | src ----------------

__global__ __launch_bounds__(256) void k_bin(const int* __restrict__ src,
                                             const int* __restrict__ dst, int E,
                                             const int* __restrict__ blockbase,
                                             const int* __restrict__ bsumB,
                                             unsigned int* __restrict__ bin) {
    __shared__ int s[256], exs[NBUK + 1];
    __shared__ int baseL[NBUK], rankL[NBUK];
    int t = threadIdx.x;
    bucket_scan(bsumB, s, exs, t);
    if (t < NBUK) {
        baseL[t] = exs[t] + blockbase[blockIdx.x * NBUK + t];
        rankL[t] = 0;
    }
    __syncthreads();
    int base = blockIdx.x * 4096;
    for (int j = 0; j < 16; j++) {
        int e = base + j * 256 + t;
        if (e < E) {
            int sv = src[e], d = dst[e];
            int bu = d >> BSH;
            int r = atomicAdd(&rankL[bu], 1);
            bin[baseL[bu] + r] = ((unsigned int)(d & 511) << 17) | (unsigned int)sv;
        }
    }
}

// ---------------- cntscan: per-bucket counts + scan -> FINAL row_ptr + dinv ----------------

__global__ __launch_bounds__(256) void k_cntscan(const unsigned int* __restrict__ bin,
                                                 const int* __restrict__ bsumB,
                                                 int* __restrict__ row_ptr,
                                                 float* __restrict__ dinv) {
    __shared__ int sb[256], exs[NBUK + 1];
    __shared__ int c[512];
    __shared__ int s[256];
    int b = blockIdx.x, t = threadIdx.x;
    bucket_scan(bsumB, sb, exs, t);
    int lo = exs[b], hi = exs[b + 1];
    c[t] = 0;
    c[t + 256] = 0;
    __syncthreads();
    for (int e = lo + t; e < hi; e += 256) atomicAdd(&c[bin[e] >> 17], 1);
    __syncthreads();
    int a0 = c[2 * t], a1 = c[2 * t + 1];
    s[t] = a0 + a1;
    __syncthreads();
    for (int off = 1; off < 256; off <<= 1) {
        int u = (t >= off) ? s[t - off] : 0;
        __syncthreads();
        s[t] += u;
        __syncthreads();
    }
    int ex = (t > 0) ? s[t - 1] : 0;
    int n0 = (b << BSH) + 2 * t;
    if (n0 < N_NODES) {
        row_ptr[n0] = lo + ex;  // FINAL global edge offset
        dinv[n0] = rsqrtf((float)a0 + 1.0f);
    }
    if (n0 + 1 < N_NODES) {
        row_ptr[n0 + 1] = lo + ex + a0;
        dinv[n0 + 1] = rsqrtf((float)a1 + 1.0f);
    }
    if (b == NBUK - 1 && t == 255) row_ptr[N_NODES] = exs[NBUK];  // sentinel = E
}

// ---------------- place: cursors from final row_ptr; write cw ----------------

__global__ __launch_bounds__(256) void k_place(const unsigned int* __restrict__ bin,
                                               const int* __restrict__ bsumB,
                                               const int* __restrict__ row_ptr,
                                               const float* __restrict__ dinv,
                                               int2* __restrict__ cw) {
    __shared__ int sb[256], exs[NBUK + 1];
    __shared__ int cur[512];
    __shared__ float dl[512];
    int b = blockIdx.x, t = threadIdx.x;
    bucket_scan(bsumB, sb, exs, t);
    int node0 = b << BSH;
    int nbn = N_NODES - node0;
    if (nbn > 512) nbn = 512;
    if (t < nbn) {
        cur[t] = row_ptr[node0 + t];
        dl[t] = dinv[node0 + t];
    }
    if (t + 256 < nbn) {
        cur[t + 256] = row_ptr[node0 + t + 256];
        dl[t + 256] = dinv[node0 + t + 256];
    }
    __syncthreads();
    int lo = exs[b], hi = exs[b + 1];
    for (int e = lo + t; e < hi; e += 256) {
        unsigned int rec = bin[e];
        int sv = rec & 0x1FFFF;
        int dloc = rec >> 17;
        int pos = atomicAdd(&cur[dloc], 1);
        int2 v;
        v.x = sv;
        v.y = __float_as_int(dinv[sv] * dl[dloc]);
        cw[pos] = v;
    }
}

// ---------------- layer-1 pull: 4 nodes/wave, 16 lanes/node, shfl-broadcast cw ----------------

__global__ __launch_bounds__(256) void k_pull1(const int* __restrict__ row_ptr,
                                               const int2* __restrict__ cw,
                                               const uint4* __restrict__ xb4,
                                               const float* __restrict__ dinv,
                                               uint4* __restrict__ agg4) {
    int wave = (blockIdx.x * 256 + threadIdx.x) >> 6;
    int lane = threadIdx.x & 63;
    int g = lane >> 4, l = lane & 15;
    int gbase = g << 4;
    int node = wave * 4 + g;  // grid sized exactly
    int beg = row_ptr[node], end = row_ptr[node + 1];
    float di = dinv[node];
    float a[8] = {0, 0, 0, 0, 0, 0, 0, 0};
    fma8(a, di * di, xb4[(size_t)node * 16 + l]);

    for (int base = beg; base < end; base += 16) {
        int idx = base + l;
        int2 cl = cw[(idx < end) ? idx : beg];
        float wl = (idx < end) ? __int_as_float(cl.y) : 0.f;
        int sl = cl.x;
        int cnt = end - base;
        if (cnt > 16) cnt = 16;
        int s0 = __shfl(sl, gbase + 0), s1 = __shfl(sl, gbase + 1);
        int s2 = __shfl(sl, gbase + 2), s3 = __shfl(sl, gbase + 3);
        float w0 = __shfl(wl, gbase + 0), w1 = __shfl(wl, gbase + 1);
        float w2 = __shfl(wl, gbase + 2), w3 = __shfl(wl, gbase + 3);
        uint4 u0 = xb4[(size_t)s0 * 16 + l];
        uint4 u1 = xb4[(size_t)s1 * 16 + l];
        uint4 u2 = xb4[(size_t)s2 * 16 + l];
        uint4 u3 = xb4[(size_t)s3 * 16 + l];
        for (int j = 4; j < cnt; j += 4) {
            int t0 = __shfl(sl, gbase + j + 0), t1 = __shfl(sl, gbase + j + 1);
            int t2 = __shfl(sl, gbase + j + 2), t3 = __shfl(sl, gbase + j + 3);
            float x0 = __shfl(wl, gbase + j + 0), x1 = __shfl(wl, gbase + j + 1);
            float x2 = __shfl(wl, gbase + j + 2), x3 = __shfl(wl, gbase + j + 3);
            uint4 v0 = xb4[(size_t)t0 * 16 + l];
            uint4 v1 = xb4[(size_t)t1 * 16 + l];
            uint4 v2 = xb4[(size_t)t2 * 16 + l];
            uint4 v3 = xb4[(size_t)t3 * 16 + l];
            fma8(a, w0, u0);
            fma8(a, w1, u1);
            fma8(a, w2, u2);
            fma8(a, w3, u3);
            s0 = t0; s1 = t1; s2 = t2; s3 = t3;
            w0 = x0; w1 = x1; w2 = x2; w3 = x3;
            u0 = v0; u1 = v1; u2 = v2; u3 = v3;
        }
        fma8(a, w0, u0);
        fma8(a, w1, u1);
        fma8(a, w2, u2);
        fma8(a, w3, u3);
    }
    uint4 o;
    o.x = (unsigned int)f2bf(a[0]) | ((unsigned int)f2bf(a[1]) << 16);
    o.y = (unsigned int)f2bf(a[2]) | ((unsigned int)f2bf(a[3]) << 16);
    o.z = (unsigned int)f2bf(a[4]) | ((unsigned int)f2bf(a[5]) << 16);
    o.w = (unsigned int)f2bf(a[6]) | ((unsigned int)f2bf(a[7]) << 16);
    agg4[(size_t)node * 16 + l] = o;
}

// ---------------- fused GEMM chain (MFMA): 3 tiles/block, double-buffered sH, 1 barrier/tile ----
// weights hoisted once per block (amortized over 3 tiles); A direct from global (L2-hot);
// m written COMPACT (N x 64 bf16). 1042 blocks -> ~4 blocks/CU resident.

__global__ __launch_bounds__(256) void k_fused_mfma(const unsigned short* __restrict__ agg,
                                                    const unsigned short* __restrict__ W1t,
                                                    const float* __restrict__ b1,
                                                    const unsigned short* __restrict__ W2t,
                                                    unsigned short* __restrict__ mb) {
    __shared__ char sH[2][TR * HID * 2];   // 2 x 16 KB, row stride 512B
    int t = threadIdx.x, wave = t >> 6, lane = t & 63;
    int lr = lane & 15, lg = lane >> 4;

    bf8 w1f[4][4];
#pragma unroll
    for (int kk = 0; kk < 4; kk++)
#pragma unroll
        for (int tt = 0; tt < 4; tt++)
            w1f[kk][tt] = *(const bf8*)(W1t + (size_t)(wave * 64 + tt * 16 + lr) * D_IN + kk * 32 + lg * 8);
    bf8 w2f[8];
#pragma unroll
    for (int kk = 0; kk < 8; kk++)
        w2f[kk] = *(const bf8*)(W2t + (size_t)(wave * 16 + lr) * HID + kk * 32 + lg * 8);
    float bias[4];
#pragma unroll
    for (int tt = 0; tt < 4; tt++) bias[tt] = b1[wave * 64 + tt * 16 + lr];

    for (int it = 0; it < TPB; it++) {
        int tile = blockIdx.x * TPB + it;
        if (tile >= 3125) break;  // uniform per block
        size_t row0 = (size_t)tile * TR;
        char* sHb = sH[it & 1];

        f4 acc1[4][2];
#pragma unroll
        for (int tt = 0; tt < 4; tt++)
#pragma unroll
            for (int h = 0; h < 2; h++) acc1[tt][h] = (f4){0.f, 0.f, 0.f, 0.f};

#pragma unroll
        for (int kk = 0; kk < 4; kk++) {
            bf8 a0 = *(const bf8*)(agg + (row0 + lr) * 128 + kk * 32 + lg * 8);
            bf8 a1 = *(const bf8*)(agg + (row0 + 16 + lr) * 128 + kk * 32 + lg * 8);
#pragma unroll
            for (int tt = 0; tt < 4; tt++) {
                acc1[tt][0] = __builtin_amdgcn_mfma_f32_16x16x32_bf16(a0, w1f[kk][tt], acc1[tt][0], 0, 0, 0);
                acc1[tt][1] = __builtin_amdgcn_mfma_f32_16x16x32_bf16(a1, w1f[kk][tt], acc1[tt][1], 0, 0, 0);
            }
        }

#pragma unroll
        for (int tt = 0; tt < 4; tt++) {
            int colc = wave * 64 + tt * 16 + lr;
#pragma unroll
            for (int h = 0; h < 2; h++) {
#pragma unroll
                for (int ri = 0; ri < 4; ri++) {
                    int row = h * 16 + lg * 4 + ri;
                    float hv = acc1[tt][h][ri] + bias[tt];
                    hv = hv > 0.f ? hv : 0.f;
                    *(unsigned short*)(sHb + ((row * 512 + colc * 2) ^ ((row & 7) << 4))) = f2bf(hv);
                }
            }
        }
        __syncthreads();  // sHb complete; double-buffering makes this the ONLY barrier

        f4 acc2[2];
        acc2[0] = (f4){0.f, 0.f, 0.f, 0.f};
        acc2[1] = (f4){0.f, 0.f, 0.f, 0.f};
#pragma unroll
        for (int kk = 0; kk < 8; kk++) {
            bf8 a0 = *(const bf8*)(sHb + ((lr * 512 + kk * 64 + lg * 16) ^ ((lr & 7) << 4)));
            bf8 a1 = *(const bf8*)(sHb + (((16 + lr) * 512 + kk * 64 + lg * 16) ^ (((16 + lr) & 7) << 4)));
            acc2[0] = __builtin_amdgcn_mfma_f32_16x16x32_bf16(a0, w2f[kk], acc2[0], 0, 0, 0);
            acc2[1] = __builtin_amdgcn_mfma_f32_16x16x32_bf16(a1, w2f[kk], acc2[1], 0, 0, 0);
        }
        int colc = wave * 16 + lr;
#pragma unroll
        for (int h = 0; h < 2; h++)
#pragma unroll
            for (int ri = 0; ri < 4; ri++) {
                int row = h * 16 + lg * 4 + ri;
                mb[(row0 + row) * D_OUT + colc] = f2bf(acc2[h][ri]);
            }
    }
}

// ---------------- layer-2 pull: 4 nodes/wave, 16 lanes/node, shfl-broadcast cw ----------------
// m rows: COMPACT 64 bf16 = 16 uint2 per row (12.8 MB working set)

__global__ __launch_bounds__(256) void k_pull2(const int* __restrict__ row_ptr,
                                               const int2* __restrict__ cw,
                                               const uint2* __restrict__ m2,
                                               const float* __restrict__ dinv,
                                               const float* __restrict__ b2,
                                               float4* __restrict__ out4) {
    int wave = (blockIdx.x * 256 + threadIdx.x) >> 6;
    int lane = threadIdx.x & 63;
    int g = lane >> 4, l = lane & 15;
    int gbase = g << 4;
    int node = wave * 4 + g;
    int beg = row_ptr[node], end = row_ptr[node + 1];
    float di = dinv[node];
    float a[4] = {0, 0, 0, 0};
    fma4(a, di * di, m2[(size_t)node * 16 + l]);

    for (int base = beg; base < end; base += 16) {
        int idx = base + l;
        int2 cl = cw[(idx < end) ? idx : beg];
        float wl = (idx < end) ? __int_as_float(cl.y) : 0.f;
        int sl = cl.x;
        int cnt = end - base;
        if (cnt > 16) cnt = 16;
        int s0 = __shfl(sl, gbase + 0), s1 = __shfl(sl, gbase + 1);
        int s2 = __shfl(sl, gbase + 2), s3 = __shfl(sl, gbase + 3);
        float w0 = __shfl(wl, gbase + 0), w1 = __shfl(wl, gbase + 1);
        float w2 = __shfl(wl, gbase + 2), w3 = __shfl(wl, gbase + 3);
        uint2 u0 = m2[(size_t)s0 * 16 + l];
        uint2 u1 = m2[(size_t)s1 * 16 + l];
        uint2 u2 = m2[(size_t)s2 * 16 + l];
        uint2 u3 = m2[(size_t)s3 * 16 + l];
        for (int j = 4; j < cnt; j += 4) {
            int t0 = __shfl(sl, gbase + j + 0), t1 = __shfl(sl, gbase + j + 1);
            int t2 = __shfl(sl, gbase + j + 2), t3 = __shfl(sl, gbase + j + 3);
            float x0 = __shfl(wl, gbase + j + 0), x1 = __shfl(wl, gbase + j + 1);
            float x2 = __shfl(wl, gbase + j + 2), x3 = __shfl(wl, gbase + j + 3);
            uint2 v0 = m2[(size_t)t0 * 16 + l];
            uint2 v1 = m2[(size_t)t1 * 16 + l];
            uint2 v2 = m2[(size_t)t2 * 16 + l];
            uint2 v3 = m2[(size_t)t3 * 16 + l];
            fma4(a, w0, u0);
            fma4(a, w1, u1);
            fma4(a, w2, u2);
            fma4(a, w3, u3);
            s0 = t0; s1 = t1; s2 = t2; s3 = t3;
            w0 = x0; w1 = x1; w2 = x2; w3 = x3;
            u0 = v0; u1 = v1; u2 = v2; u3 = v3;
        }
        fma4(a, w0, u0);
        fma4(a, w1, u1);
        fma4(a, w2, u2);
        fma4(a, w3, u3);
    }
    float4 bv = ((const float4*)b2)[l];
    float4 o;
    o.x = a[0] + bv.x;
    o.y = a[1] + bv.y;
    o.z = a[2] + bv.z;
    o.w = a[3] + bv.w;
    out4[(size_t)node * 16 + l] = o;
}

// ---------------- launch ----------------

extern "C" void kernel_launch(void* const* d_in, const int* in_sizes, int n_in,
                              void* d_out, int out_size, void* d_ws, size_t ws_size,
                              hipStream_t stream) {
    const float* x  = (const float*)d_in[0];
    const int*   ei = (const int*)d_in[1];
    const float* W1 = (const float*)d_in[2];
    const float* b1 = (const float*)d_in[3];
    const float* W2 = (const float*)d_in[4];
    const float* b2 = (const float*)d_in[5];
    float* out = (float*)d_out;

    const int E = in_sizes[1] / 2;
    const int* src = ei;
    const int* dst = ei + E;

    // workspace layout — ends at 71,299,328 B (d_ws = 256 MiB per harness poison fills)
    char* ws = (char*)d_ws;
    int* row_ptr        = (int*)(ws + 0);              // 100001 ints
    int2* cw            = (int2*)(ws + 400640);        // 800000 int2 (6.4 MB)
    float* dinv         = (float*)(ws + 6800640);      // 100000 f
    unsigned short* W1t = (unsigned short*)(ws + 7201024);   // 256*128 bf16
    unsigned short* W2t = (unsigned short*)(ws + 7266560);   // 64*256 bf16
    unsigned short* xb  = (unsigned short*)(ws + 7299328);   // N*128 bf16 (25.6 MB)
    unsigned short* aggb = (unsigned short*)(ws + 32899328); // N*128 bf16 (25.6 MB)
    unsigned short* mb  = (unsigned short*)(ws + 58499328);  // N*64 bf16 (12.8 MB) compact m
    // scratch aliased into aggb region (all dead before k_pull1 writes aggb)
    unsigned int* bin   = (unsigned int*)aggb;                    // E uints (3.2 MB)
    int* hist2d         = (int*)((char*)aggb + 3200256);          // NBB*NBUK ints
    int* blockbase      = (int*)((char*)aggb + 3354112);          // NBB*NBUK ints
    int* bsumB          = (int*)((char*)aggb + 3507968);          // NBUK ints

    const int NBB = (E + 4095) / 4096;  // 196 edge blocks

    // 1. prep: cvt_x | cvt_w1 | cvt_w2 | hist2d rows
    k_prep<<<12692 + NBB, 256, 0, stream>>>(x, (unsigned long long*)xb, W1, W1t, W2, W2t,
                                            dst, E, hist2d);
    // 2. per-bucket scan over edge-blocks
    k_scanB1<<<NBUK, 256, 0, stream>>>(hist2d, blockbase, bsumB, NBB);
    // 3. bin edges by dst bucket
    k_bin<<<NBB, 256, 0, stream>>>(src, dst, E, blockbase, bsumB, bin);
    // 4. per-bucket counts + scan -> FINAL row_ptr + dinv
    k_cntscan<<<NBUK, 256, 0, stream>>>(bin, bsumB, row_ptr, dinv);
    // 5. place cw records
    k_place<<<NBUK, 256, 0, stream>>>(bin, bsumB, row_ptr, dinv, cw);
    // 6. layer-1 pull (shfl-broadcast cw, SW-pipelined gathers)
    k_pull1<<<6250, 256, 0, stream>>>(row_ptr, cw, (const uint4*)xb, dinv, (uint4*)aggb);
    // 7. fused MFMA GEMM chain -> compact m (3 tiles/block, dbuf sH, 1 barrier/tile)
    k_fused_mfma<<<MGRID, 256, 0, stream>>>(aggb, W1t, b1, W2t, mb);
    // 8. layer-2 pull (compact m gathers)
    k_pull2<<<6250, 256, 0, stream>>>(row_ptr, cw, (const uint2*)mb, dinv, b2, (float4*)out);
}

// Round 20
// 136.583 us; speedup vs baseline: 1.1689x; 1.0645x over previous
//
#include <hip/hip_runtime.h>
#include <hip/hip_bf16.h>

#define N_NODES 100000
#define D_IN 128
#define HID 256
#define D_OUT 64
#define TR 32
#define NBUK 196   // dst>>9 buckets of 512 nodes
#define BSH 9
#define MGRID 625  // 5 tiles per block
#define TPB 5

typedef __attribute__((ext_vector_type(8))) short bf8;
typedef __attribute__((ext_vector_type(4))) float f4;

static __device__ __forceinline__ unsigned short f2bf(float f) {
    __hip_bfloat16 h = __float2bfloat16(f);
    return *reinterpret_cast<unsigned short*>(&h);
}
static __device__ __forceinline__ float bflo(unsigned int u) { return __uint_as_float(u << 16); }
static __device__ __forceinline__ float bfhi(unsigned int u) { return __uint_as_float(u & 0xffff0000u); }

static __device__ __forceinline__ void fma8(float* a, float w, uint4 u) {
    a[0] += w * bflo(u.x); a[1] += w * bfhi(u.x);
    a[2] += w * bflo(u.y); a[3] += w * bfhi(u.y);
    a[4] += w * bflo(u.z); a[5] += w * bfhi(u.z);
    a[6] += w * bflo(u.w); a[7] += w * bfhi(u.w);
}
static __device__ __forceinline__ void fma4(float* a, float w, uint2 u) {
    a[0] += w * bflo(u.x); a[1] += w * bfhi(u.x);
    a[2] += w * bflo(u.y); a[3] += w * bfhi(u.y);
}

// ---------------- fused prep: cvt_x | cvt_w1 | cvt_w2 | per-block bucket histograms ----------------

__global__ __launch_bounds__(256) void k_prep(const float* __restrict__ x,
                                              unsigned long long* __restrict__ xb,
                                              const float* __restrict__ W1,
                                              unsigned short* __restrict__ W1t,
                                              const float* __restrict__ W2,
                                              unsigned short* __restrict__ W2t,
                                              const int* __restrict__ dst, int E,
                                              int* __restrict__ hist2d) {
    int b = blockIdx.x, t = threadIdx.x;
    if (b < 12500) {
        int i = b * 256 + t;  // float4 index over x
        float4 v = ((const float4*)x)[i];
        unsigned long long o = (unsigned long long)f2bf(v.x) |
                               ((unsigned long long)f2bf(v.y) << 16) |
                               ((unsigned long long)f2bf(v.z) << 32) |
                               ((unsigned long long)f2bf(v.w) << 48);
        xb[i] = o;
    } else if (b < 12628) {
        int i = (b - 12500) * 256 + t;
        int n = i >> 7, k = i & 127;
        W1t[i] = f2bf(W1[k * HID + n]);
    } else if (b < 12692) {
        int i = (b - 12628) * 256 + t;
        int n = i >> 8, k = i & 255;
        W2t[i] = f2bf(W2[k * D_OUT + n]);
    } else {
        int hb = b - 12692;
        __shared__ int h[NBUK];
        if (t < NBUK) h[t] = 0;
        __syncthreads();
        int base = hb * 4096;
        for (int j = 0; j < 16; j++) {
            int e = base + j * 256 + t;
            if (e < E) atomicAdd(&h[dst[e] >> BSH], 1);
        }
        __syncthreads();
        if (t < NBUK) hist2d[hb * NBUK + t] = h[t];
    }
}

// ---------------- scanB1: per-bucket scan over edge-blocks (grid = NBUK) ----------------

__global__ __launch_bounds__(256) void k_scanB1(const int* __restrict__ hist2d,
                                                int* __restrict__ blockbase,
                                                int* __restrict__ bsumB, int nbb) {
    __shared__ int s[256];
    int u = blockIdx.x, t = threadIdx.x;
    int v = (t < nbb) ? hist2d[t * NBUK + u] : 0;
    s[t] = v;
    __syncthreads();
    for (int off = 1; off < 256; off <<= 1) {
        int w = (t >= off) ? s[t - off] : 0;
        __syncthreads();
        s[t] += w;
        __syncthreads();
    }
    if (t < nbb) blockbase[t * NBUK + u] = s[t] - v;  // exclusive, bucket-local
    if (t == 255) bsumB[u] = s[255];                  // bucket total
}

// local exclusive scan of bucket totals into exs[0..NBUK]
static __device__ __forceinline__ void bucket_scan(const int* __restrict__ bsumB,
                                                   int* s, int* exs, int t) {
    int v = (t < NBUK) ? bsumB[t] : 0;
    s[t] = v;
    __syncthreads();
    for (int off = 1; off < 256; off <<= 1) {
        int w = (t >= off) ? s[t - off] : 0;
        __syncthreads();
        s[t] += w;
        __syncthreads();
    }
    if (t < NBUK) exs[t] = s[t] - v;
    if (t == NBUK - 1) exs[NBUK] = s[t];
    __syncthreads();
}

// ---------------- bin: deterministic bases, LDS rank only. record = (dst&511)<<17 | src ----------------

__global__ __launch_bounds__(256) void k_bin(const int* __restrict__ src,
                                             const int* __restrict__ dst, int E,
                                             const int* __restrict__ blockbase,
                                             const int* __restrict__ bsumB,
                                             unsigned int* __restrict__ bin) {
    __shared__ int s[256], exs[NBUK + 1];
    __shared__ int baseL[NBUK], rankL[NBUK];
    int t = threadIdx.x;
    bucket_scan(bsumB, s, exs, t);
    if (t < NBUK) {
        baseL[t] = exs[t] + blockbase[blockIdx.x * NBUK + t];
        rankL[t] = 0;
    }
    __syncthreads();
    int base = blockIdx.x * 4096;
    for (int j = 0; j < 16; j++) {
        int e = base + j * 256 + t;
        if (e < E) {
            int sv = src[e], d = dst[e];
            int bu = d >> BSH;
            int r = atomicAdd(&rankL[bu], 1);
            bin[baseL[bu] + r] = ((unsigned int)(d & 511) << 17) | (unsigned int)sv;
        }
    }
}

// ---------------- cntscan: per-bucket counts + scan -> FINAL row_ptr + dinv ----------------

__global__ __launch_bounds__(256) void k_cntscan(const unsigned int* __restrict__ bin,
                                                 const int* __restrict__ bsumB,
                                                 int* __restrict__ row_ptr,
                                                 float* __restrict__ dinv) {
    __shared__ int sb[256], exs[NBUK + 1];
    __shared__ int c[512];
    __shared__ int s[256];
    int b = blockIdx.x, t = threadIdx.x;
    bucket_scan(bsumB, sb, exs, t);
    int lo = exs[b], hi = exs[b + 1];
    c[t] = 0;
    c[t + 256] = 0;
    __syncthreads();
    for (int e = lo + t; e < hi; e += 256) atomicAdd(&c[bin[e] >> 17], 1);
    __syncthreads();
    int a0 = c[2 * t], a1 = c[2 * t + 1];
    s[t] = a0 + a1;
    __syncthreads();
    for (int off = 1; off < 256; off <<= 1) {
        int u = (t >= off) ? s[t - off] : 0;
        __syncthreads();
        s[t] += u;
        __syncthreads();
    }
    int ex = (t > 0) ? s[t - 1] : 0;
    int n0 = (b << BSH) + 2 * t;
    if (n0 < N_NODES) {
        row_ptr[n0] = lo + ex;  // FINAL global edge offset
        dinv[n0] = rsqrtf((float)a0 + 1.0f);
    }
    if (n0 + 1 < N_NODES) {
        row_ptr[n0 + 1] = lo + ex + a0;
        dinv[n0 + 1] = rsqrtf((float)a1 + 1.0f);
    }
    if (b == NBUK - 1 && t == 255) row_ptr[N_NODES] = exs[NBUK];  // sentinel = E
}

// ---------------- place: cursors from final row_ptr; write cw ----------------

__global__ __launch_bounds__(256) void k_place(const unsigned int* __restrict__ bin,
                                               const int* __restrict__ bsumB,
                                               const int* __restrict__ row_ptr,
                                               const float* __restrict__ dinv,
                                               int2* __restrict__ cw) {
    __shared__ int sb[256], exs[NBUK + 1];
    __shared__ int cur[512];
    __shared__ float dl[512];
    int b = blockIdx.x, t = threadIdx.x;
    bucket_scan(bsumB, sb, exs, t);
    int node0 = b << BSH;
    int nbn = N_NODES - node0;
    if (nbn > 512) nbn = 512;
    if (t < nbn) {
        cur[t] = row_ptr[node0 + t];
        dl[t] = dinv[node0 + t];
    }
    if (t + 256 < nbn) {
        cur[t + 256] = row_ptr[node0 + t + 256];
        dl[t + 256] = dinv[node0 + t + 256];
    }
    __syncthreads();
    int lo = exs[b], hi = exs[b + 1];
    for (int e = lo + t; e < hi; e += 256) {
        unsigned int rec = bin[e];
        int sv = rec & 0x1FFFF;
        int dloc = rec >> 17;
        int pos = atomicAdd(&cur[dloc], 1);
        int2 v;
        v.x = sv;
        v.y = __float_as_int(dinv[sv] * dl[dloc]);
        cw[pos] = v;
    }
}

// ---------------- layer-1 pull: 4 nodes/wave, 16 lanes/node, shfl-broadcast cw ----------------

__global__ __launch_bounds__(256) void k_pull1(const int* __restrict__ row_ptr,
                                               const int2* __restrict__ cw,
                                               const uint4* __restrict__ xb4,
                                               const float* __restrict__ dinv,
                                               uint4* __restrict__ agg4) {
    int wave = (blockIdx.x * 256 + threadIdx.x) >> 6;
    int lane = threadIdx.x & 63;
    int g = lane >> 4, l = lane & 15;
    int gbase = g << 4;
    int node = wave * 4 + g;  // grid sized exactly
    int beg = row_ptr[node], end = row_ptr[node + 1];
    float di = dinv[node];
    float a[8] = {0, 0, 0, 0, 0, 0, 0, 0};
    fma8(a, di * di, xb4[(size_t)node * 16 + l]);

    for (int base = beg; base < end; base += 16) {
        int idx = base + l;
        int2 cl = cw[(idx < end) ? idx : beg];
        float wl = (idx < end) ? __int_as_float(cl.y) : 0.f;
        int sl = cl.x;
        int cnt = end - base;
        if (cnt > 16) cnt = 16;
        int s0 = __shfl(sl, gbase + 0), s1 = __shfl(sl, gbase + 1);
        int s2 = __shfl(sl, gbase + 2), s3 = __shfl(sl, gbase + 3);
        float w0 = __shfl(wl, gbase + 0), w1 = __shfl(wl, gbase + 1);
        float w2 = __shfl(wl, gbase + 2), w3 = __shfl(wl, gbase + 3);
        uint4 u0 = xb4[(size_t)s0 * 16 + l];
        uint4 u1 = xb4[(size_t)s1 * 16 + l];
        uint4 u2 = xb4[(size_t)s2 * 16 + l];
        uint4 u3 = xb4[(size_t)s3 * 16 + l];
        for (int j = 4; j < cnt; j += 4) {
            int t0 = __shfl(sl, gbase + j + 0), t1 = __shfl(sl, gbase + j + 1);
            int t2 = __shfl(sl, gbase + j + 2), t3 = __shfl(sl, gbase + j + 3);
            float x0 = __shfl(wl, gbase + j + 0), x1 = __shfl(wl, gbase + j + 1);
            float x2 = __shfl(wl, gbase + j + 2), x3 = __shfl(wl, gbase + j + 3);
            uint4 v0 = xb4[(size_t)t0 * 16 + l];
            uint4 v1 = xb4[(size_t)t1 * 16 + l];
            uint4 v2 = xb4[(size_t)t2 * 16 + l];
            uint4 v3 = xb4[(size_t)t3 * 16 + l];
            fma8(a, w0, u0);
            fma8(a, w1, u1);
            fma8(a, w2, u2);
            fma8(a, w3, u3);
            s0 = t0; s1 = t1; s2 = t2; s3 = t3;
            w0 = x0; w1 = x1; w2 = x2; w3 = x3;
            u0 = v0; u1 = v1; u2 = v2; u3 = v3;
        }
        fma8(a, w0, u0);
        fma8(a, w1, u1);
        fma8(a, w2, u2);
        fma8(a, w3, u3);
    }
    uint4 o;
    o.x = (unsigned int)f2bf(a[0]) | ((unsigned int)f2bf(a[1]) << 16);
    o.y = (unsigned int)f2bf(a[2]) | ((unsigned int)f2bf(a[3]) << 16);
    o.z = (unsigned int)f2bf(a[4]) | ((unsigned int)f2bf(a[5]) << 16);
    o.w = (unsigned int)f2bf(a[6]) | ((unsigned int)f2bf(a[7]) << 16);
    agg4[(size_t)node * 16 + l] = o;
}

// ---------------- fused GEMM chain (MFMA): 5 tiles/block, dbuf sH (1 barrier/tile),
// A-register prefetch one tile ahead (issue-early / consume-late). Compact mb out.

__global__ __launch_bounds__(256) void k_fused_mfma(const unsigned short* __restrict__ agg,
                                                    const unsigned short* __restrict__ W1t,
                                                    const float* __restrict__ b1,
                                                    const unsigned short* __restrict__ W2t,
                                                    unsigned short* __restrict__ mb) {
    __shared__ char sH[2][TR * HID * 2];   // 2 x 16 KB
    int t = threadIdx.x, wave = t >> 6, lane = t & 63;
    int lr = lane & 15, lg = lane >> 4;

    bf8 w1f[4][4];
#pragma unroll
    for (int kk = 0; kk < 4; kk++)
#pragma unroll
        for (int tt = 0; tt < 4; tt++)
            w1f[kk][tt] = *(const bf8*)(W1t + (size_t)(wave * 64 + tt * 16 + lr) * D_IN + kk * 32 + lg * 8);
    bf8 w2f[8];
#pragma unroll
    for (int kk = 0; kk < 8; kk++)
        w2f[kk] = *(const bf8*)(W2t + (size_t)(wave * 16 + lr) * HID + kk * 32 + lg * 8);
    float bias[4];
#pragma unroll
    for (int tt = 0; tt < 4; tt++) bias[tt] = b1[wave * 64 + tt * 16 + lr];

    // prefetch A for tile 0
    bf8 pa0[4], pa1[4];
    {
        size_t r0 = (size_t)blockIdx.x * TR;  // tile index = blockIdx.x + 0*MGRID
#pragma unroll
        for (int kk = 0; kk < 4; kk++) {
            pa0[kk] = *(const bf8*)(agg + (r0 + lr) * 128 + kk * 32 + lg * 8);
            pa1[kk] = *(const bf8*)(agg + (r0 + 16 + lr) * 128 + kk * 32 + lg * 8);
        }
    }

    for (int it = 0; it < TPB; it++) {
        size_t row0 = ((size_t)blockIdx.x + (size_t)it * MGRID) * TR;
        char* sHb = sH[it & 1];

        // GEMM1 from prefetched A
        f4 acc1[4][2];
#pragma unroll
        for (int tt = 0; tt < 4; tt++)
#pragma unroll
            for (int h = 0; h < 2; h++) acc1[tt][h] = (f4){0.f, 0.f, 0.f, 0.f};

#pragma unroll
        for (int kk = 0; kk < 4; kk++) {
#pragma unroll
            for (int tt = 0; tt < 4; tt++) {
                acc1[tt][0] = __builtin_amdgcn_mfma_f32_16x16x32_bf16(pa0[kk], w1f[kk][tt], acc1[tt][0], 0, 0, 0);
                acc1[tt][1] = __builtin_amdgcn_mfma_f32_16x16x32_bf16(pa1[kk], w1f[kk][tt], acc1[tt][1], 0, 0, 0);
            }
        }

        // issue next tile's A-loads NOW (hide HBM latency under epilogue+GEMM2)
        if (it + 1 < TPB) {
            size_t r1 = ((size_t)blockIdx.x + (size_t)(it + 1) * MGRID) * TR;
#pragma unroll
            for (int kk = 0; kk < 4; kk++) {
                pa0[kk] = *(const bf8*)(agg + (r1 + lr) * 128 + kk * 32 + lg * 8);
                pa1[kk] = *(const bf8*)(agg + (r1 + 16 + lr) * 128 + kk * 32 + lg * 8);
            }
        }

        // epilogue 1: bias + relu + bf16 -> sHb (XOR swizzle)
#pragma unroll
        for (int tt = 0; tt < 4; tt++) {
            int colc = wave * 64 + tt * 16 + lr;
#pragma unroll
            for (int h = 0; h < 2; h++) {
#pragma unroll
                for (int ri = 0; ri < 4; ri++) {
                    int row = h * 16 + lg * 4 + ri;
                    float hv = acc1[tt][h][ri] + bias[tt];
                    hv = hv > 0.f ? hv : 0.f;
                    *(unsigned short*)(sHb + ((row * 512 + colc * 2) ^ ((row & 7) << 4))) = f2bf(hv);
                }
            }
        }
        __syncthreads();  // only barrier per tile (dbuf protects previous tile's reads)

        f4 acc2[2];
        acc2[0] = (f4){0.f, 0.f, 0.f, 0.f};
        acc2[1] = (f4){0.f, 0.f, 0.f, 0.f};
#pragma unroll
        for (int kk = 0; kk < 8; kk++) {
            bf8 a0 = *(const bf8*)(sHb + ((lr * 512 + kk * 64 + lg * 16) ^ ((lr & 7) << 4)));
            bf8 a1 = *(const bf8*)(sHb + (((16 + lr) * 512 + kk * 64 + lg * 16) ^ (((16 + lr) & 7) << 4)));
            acc2[0] = __builtin_amdgcn_mfma_f32_16x16x32_bf16(a0, w2f[kk], acc2[0], 0, 0, 0);
            acc2[1] = __builtin_amdgcn_mfma_f32_16x16x32_bf16(a1, w2f[kk], acc2[1], 0, 0, 0);
        }
        int colc = wave * 16 + lr;
#pragma unroll
        for (int h = 0; h < 2; h++)
#pragma unroll
            for (int ri = 0; ri < 4; ri++) {
                int row = h * 16 + lg * 4 + ri;
                mb[(row0 + row) * D_OUT + colc] = f2bf(acc2[h][ri]);
            }
    }
}

// ---------------- layer-2 pull: 4 nodes/wave, 16 lanes/node, shfl-broadcast cw ----------------
// m rows: COMPACT 64 bf16 = 16 uint2 per row (12.8 MB working set)

__global__ __launch_bounds__(256) void k_pull2(const int* __restrict__ row_ptr,
                                               const int2* __restrict__ cw,
                                               const uint2* __restrict__ m2,
                                               const float* __restrict__ dinv,
                                               const float* __restrict__ b2,
                                               float4* __restrict__ out4) {
    int wave = (blockIdx.x * 256 + threadIdx.x) >> 6;
    int lane = threadIdx.x & 63;
    int g = lane >> 4, l = lane & 15;
    int gbase = g << 4;
    int node = wave * 4 + g;
    int beg = row_ptr[node], end = row_ptr[node + 1];
    float di = dinv[node];
    float a[4] = {0, 0, 0, 0};
    fma4(a, di * di, m2[(size_t)node * 16 + l]);

    for (int base = beg; base < end; base += 16) {
        int idx = base + l;
        int2 cl = cw[(idx < end) ? idx : beg];
        float wl = (idx < end) ? __int_as_float(cl.y) : 0.f;
        int sl = cl.x;
        int cnt = end - base;
        if (cnt > 16) cnt = 16;
        int s0 = __shfl(sl, gbase + 0), s1 = __shfl(sl, gbase + 1);
        int s2 = __shfl(sl, gbase + 2), s3 = __shfl(sl, gbase + 3);
        float w0 = __shfl(wl, gbase + 0), w1 = __shfl(wl, gbase + 1);
        float w2 = __shfl(wl, gbase + 2), w3 = __shfl(wl, gbase + 3);
        uint2 u0 = m2[(size_t)s0 * 16 + l];
        uint2 u1 = m2[(size_t)s1 * 16 + l];
        uint2 u2 = m2[(size_t)s2 * 16 + l];
        uint2 u3 = m2[(size_t)s3 * 16 + l];
        for (int j = 4; j < cnt; j += 4) {
            int t0 = __shfl(sl, gbase + j + 0), t1 = __shfl(sl, gbase + j + 1);
            int t2 = __shfl(sl, gbase + j + 2), t3 = __shfl(sl, gbase + j + 3);
            float x0 = __shfl(wl, gbase + j + 0), x1 = __shfl(wl, gbase + j + 1);
            float x2 = __shfl(wl, gbase + j + 2), x3 = __shfl(wl, gbase + j + 3);
            uint2 v0 = m2[(size_t)t0 * 16 + l];
            uint2 v1 = m2[(size_t)t1 * 16 + l];
            uint2 v2 = m2[(size_t)t2 * 16 + l];
            uint2 v3 = m2[(size_t)t3 * 16 + l];
            fma4(a, w0, u0);
            fma4(a, w1, u1);
            fma4(a, w2, u2);
            fma4(a, w3, u3);
            s0 = t0; s1 = t1; s2 = t2; s3 = t3;
            w0 = x0; w1 = x1; w2 = x2; w3 = x3;
            u0 = v0; u1 = v1; u2 = v2; u3 = v3;
        }
        fma4(a, w0, u0);
        fma4(a, w1, u1);
        fma4(a, w2, u2);
        fma4(a, w3, u3);
    }
    float4 bv = ((const float4*)b2)[l];
    float4 o;
    o.x = a[0] + bv.x;
    o.y = a[1] + bv.y;
    o.z = a[2] + bv.z;
    o.w = a[3] + bv.w;
    out4[(size_t)node * 16 + l] = o;
}

// ---------------- launch ----------------

extern "C" void kernel_launch(void* const* d_in, const int* in_sizes, int n_in,
                              void* d_out, int out_size, void* d_ws, size_t ws_size,
                              hipStream_t stream) {
    const float* x  = (const float*)d_in[0];
    const int*   ei = (const int*)d_in[1];
    const float* W1 = (const float*)d_in[2];
    const float* b1 = (const float*)d_in[3];
    const float* W2 = (const float*)d_in[4];
    const float* b2 = (const float*)d_in[5];
    float* out = (float*)d_out;

    const int E = in_sizes[1] / 2;
    const int* src = ei;
    const int* dst = ei + E;

    // workspace layout — ends at 71,299,328 B (d_ws = 256 MiB per harness poison fills)
    char* ws = (char*)d_ws;
    int* row_ptr        = (int*)(ws + 0);              // 100001 ints
    int2* cw            = (int2*)(ws + 400640);        // 800000 int2 (6.4 MB)
    float* dinv         = (float*)(ws + 6800640);      // 100000 f
    unsigned short* W1t = (unsigned short*)(ws + 7201024);   // 256*128 bf16
    unsigned short* W2t = (unsigned short*)(ws + 7266560);   // 64*256 bf16
    unsigned short* xb  = (unsigned short*)(ws + 7299328);   // N*128 bf16 (25.6 MB)
    unsigned short* aggb = (unsigned short*)(ws + 32899328); // N*128 bf16 (25.6 MB)
    unsigned short* mb  = (unsigned short*)(ws + 58499328);  // N*64 bf16 (12.8 MB) compact m
    // scratch aliased into aggb region (all dead before k_pull1 writes aggb)
    unsigned int* bin   = (unsigned int*)aggb;                    // E uints (3.2 MB)
    int* hist2d         = (int*)((char*)aggb + 3200256);          // NBB*NBUK ints
    int* blockbase      = (int*)((char*)aggb + 3354112);          // NBB*NBUK ints
    int* bsumB          = (int*)((char*)aggb + 3507968);          // NBUK ints

    const int NBB = (E + 4095) / 4096;  // 196 edge blocks

    // 1. prep: cvt_x | cvt_w1 | cvt_w2 | hist2d rows
    k_prep<<<12692 + NBB, 256, 0, stream>>>(x, (unsigned long long*)xb, W1, W1t, W2, W2t,
                                            dst, E, hist2d);
    // 2. per-bucket scan over edge-blocks
    k_scanB1<<<NBUK, 256, 0, stream>>>(hist2d, blockbase, bsumB, NBB);
    // 3. bin edges by dst bucket
    k_bin<<<NBB, 256, 0, stream>>>(src, dst, E, blockbase, bsumB, bin);
    // 4. per-bucket counts + scan -> FINAL row_ptr + dinv
    k_cntscan<<<NBUK, 256, 0, stream>>>(bin, bsumB, row_ptr, dinv);
    // 5. place cw records
    k_place<<<NBUK, 256, 0, stream>>>(bin, bsumB, row_ptr, dinv, cw);
    // 6. layer-1 pull (shfl-broadcast cw, SW-pipelined gathers)
    k_pull1<<<6250, 256, 0, stream>>>(row_ptr, cw, (const uint4*)xb, dinv, (uint4*)aggb);
    // 7. fused MFMA GEMM chain -> compact m (5 tiles/block, dbuf sH, A-prefetch)
    k_fused_mfma<<<MGRID, 256, 0, stream>>>(aggb, W1t, b1, W2t, mb);
    // 8. layer-2 pull (compact m gathers)
    k_pull2<<<6250, 256, 0, stream>>>(row_ptr, cw, (const uint2*)mb, dinv, b2, (float4*)out);
}